// Round 1
// baseline (208.171 us; speedup 1.0000x reference)
//
#include <hip/hip_runtime.h>
#include <math.h>

// ConvolutionalCapsule with EM routing, fully fused: one block per output
// position (b,ho,wo). Votes V[i,c,d] (288x32x16 per position) are NEVER
// materialized: recomputed from LDS patch tile + L2-resident W each pass.
// Key algebraic facts used:
//  - reference stdv uses Rsum (not Rw) => var = unweighted sum_i (v-M)^2,
//    so S1=sum_i v, S2=sum_i v^2 are iteration-invariant (computed once).
//  - E-step softmax is over the 32 output caps => in-register half-wave
//    shuffle reduction; R is never stored (fused E+M pass).
// Thread map: t = isub*32 + c. Half-wave (32 lanes) shares one input-capsule
// index i (broadcast LDS reads, contiguous 2KB W row reads), lanes span c.

#define EPSF 1e-7f
#define KKI 288
#define NC 32
#define NTHREADS 512
#define NSUB 16        // NTHREADS/32
#define IPT 18         // KKI/NSUB

__global__ __launch_bounds__(NTHREADS)
void caps_em_kernel(const float* __restrict__ x, const float* __restrict__ Wg,
                    const float* __restrict__ beta_v, const float* __restrict__ beta_a,
                    float* __restrict__ out)
{
    __shared__ float MpL[KKI * 16];   // patch poses
    __shared__ float apL[KKI];        // patch activations
    __shared__ float T1L[NC * 16];    // sum_i Rw*v      (per iteration)
    __shared__ float S1L[NC * 16];    // sum_i v         (iteration-invariant)
    __shared__ float S2L[NC * 16];    // sum_i v^2       (iteration-invariant)
    __shared__ float RsumL[NC];
    __shared__ float ML[NC * 17];     // M (padded stride 17: bank-conflict-free)
    __shared__ float I2L[NC * 17];    // 1/(2*var)
    __shared__ float constL[NC];      // log(a_j+eps) - sum_d log(stdv+eps)
    __shared__ float aoutL[NC];       // sigmoid(a_j)

    const int t = threadIdx.x;
    const int bid = blockIdx.x;           // b*144 + ho*12 + wo
    const int b = bid / 144;
    const int rem = bid - b * 144;
    const int ho = rem / 12;
    const int wo = rem - ho * 12;

    const int c = t & 31;
    const int isub = t >> 5;

    // ---- stage patch tile: Mp[i][0..15], ap[i], i = p*32+cin, p = di*3+dj ----
    for (int idx = t; idx < KKI * 17; idx += NTHREADS) {
        int i = idx / 17;
        int e = idx - i * 17;
        int p = i >> 5, cin = i & 31;
        int di = p / 3, dj = p - di * 3;
        float vx = x[(((b * 14 + (ho + di)) * 14 + (wo + dj)) * 32 + cin) * 17 + e];
        if (e < 16) MpL[i * 16 + e] = vx; else apL[i] = vx;
    }
    for (int idx = t; idx < NC * 16; idx += NTHREADS) { T1L[idx] = 0.f; S1L[idx] = 0.f; S2L[idx] = 0.f; }
    if (t < NC) RsumL[t] = 0.f;
    __syncthreads();

    // stats phase: executed by t<32 (wave 0), one output capsule per lane
    auto stats = [&](float inv_temp) {
        if (t < NC) {
            int cc = t;
            float rsum = RsumL[cc];
            float inv_rsum = 1.f / rsum;
            float bv = beta_v[cc];
            float cost = 0.f, slog = 0.f;
            #pragma unroll
            for (int d = 0; d < 16; ++d) {
                float m = T1L[cc * 16 + d] * inv_rsum;
                // unweighted: var = sum_i (v - m)^2 = S2 - 2m S1 + KKI m^2
                float var = S2L[cc * 16 + d] - 2.f * m * S1L[cc * 16 + d] + 288.f * m * m;
                var = fmaxf(var, 0.f);
                float stdv = sqrtf(var);
                float lg = logf(stdv + EPSF);
                slog += lg;
                cost += bv + lg;
                ML[cc * 17 + d] = m;
                I2L[cc * 17 + d] = 0.5f / var;
            }
            cost *= rsum;
            float csum = cost;
            csum += __shfl_xor(csum, 16); csum += __shfl_xor(csum, 8);
            csum += __shfl_xor(csum, 4);  csum += __shfl_xor(csum, 2);
            csum += __shfl_xor(csum, 1);
            float c_mean = csum * 0.03125f;
            float diff = cost - c_mean;
            float dsq = diff * diff;
            dsq += __shfl_xor(dsq, 16); dsq += __shfl_xor(dsq, 8);
            dsq += __shfl_xor(dsq, 4);  dsq += __shfl_xor(dsq, 2);
            dsq += __shfl_xor(dsq, 1);
            float c_stdv = sqrtf(dsq * 0.03125f);
            float a_cost = beta_a[cc] + (c_mean - cost) / (c_stdv + EPSF);
            float a_j = 1.f / (1.f + expf(-inv_temp * a_cost));
            constL[cc] = logf(a_j + EPSF) - slog;
            aoutL[cc] = 1.f / (1.f + expf(-a_j));
        }
    };

    // ---- pass 0: R uniform 1/32 -> Rw = ap/32; also build S1,S2 ----
    {
        float t1[16], s1[16], s2[16];
        #pragma unroll
        for (int d = 0; d < 16; ++d) { t1[d] = 0.f; s1[d] = 0.f; s2[d] = 0.f; }
        float rsum = 0.f;
        for (int j = 0; j < IPT; ++j) {
            int i = isub * IPT + j;
            float a_i = apL[i];
            const float4* w4 = (const float4*)(Wg + (size_t)(i * NC + c) * 16);
            float wa[16], ma[16];
            ((float4*)wa)[0] = w4[0]; ((float4*)wa)[1] = w4[1];
            ((float4*)wa)[2] = w4[2]; ((float4*)wa)[3] = w4[3];
            const float4* mp4 = (const float4*)(MpL + i * 16);
            ((float4*)ma)[0] = mp4[0]; ((float4*)ma)[1] = mp4[1];
            ((float4*)ma)[2] = mp4[2]; ((float4*)ma)[3] = mp4[3];
            float v[16];
            #pragma unroll
            for (int p = 0; p < 4; ++p)
                #pragma unroll
                for (int r = 0; r < 4; ++r) {
                    float acc = ma[p * 4 + 0] * wa[0 * 4 + r];
                    acc = fmaf(ma[p * 4 + 1], wa[1 * 4 + r], acc);
                    acc = fmaf(ma[p * 4 + 2], wa[2 * 4 + r], acc);
                    acc = fmaf(ma[p * 4 + 3], wa[3 * 4 + r], acc);
                    v[p * 4 + r] = acc;
                }
            float rw = a_i * 0.03125f;
            rsum += rw;
            #pragma unroll
            for (int d = 0; d < 16; ++d) {
                t1[d] = fmaf(rw, v[d], t1[d]);
                s1[d] += v[d];
                s2[d] = fmaf(v[d], v[d], s2[d]);
            }
        }
        rsum += __shfl_xor(rsum, 32);
        #pragma unroll
        for (int d = 0; d < 16; ++d) {
            t1[d] += __shfl_xor(t1[d], 32);
            s1[d] += __shfl_xor(s1[d], 32);
            s2[d] += __shfl_xor(s2[d], 32);
        }
        if ((t & 32) == 0) {
            atomicAdd(&RsumL[c], rsum);
            #pragma unroll
            for (int d = 0; d < 16; ++d) {
                atomicAdd(&T1L[c * 16 + d], t1[d]);
                atomicAdd(&S1L[c * 16 + d], s1[d]);
                atomicAdd(&S2L[c * 16 + d], s2[d]);
            }
        }
        __syncthreads();
        stats(1.0f);   // it = 0
        __syncthreads();
    }

    // ---- passes 1,2: fused E-step (softmax over c, in-register) + M-step ----
    for (int it = 1; it < 3; ++it) {
        float Mreg[16], i2[16];
        #pragma unroll
        for (int d = 0; d < 16; ++d) { Mreg[d] = ML[c * 17 + d]; i2[d] = I2L[c * 17 + d]; }
        float Kc = constL[c];
        for (int idx = t; idx < NC * 16; idx += NTHREADS) T1L[idx] = 0.f;
        if (t < NC) RsumL[t] = 0.f;
        __syncthreads();

        float t1[16];
        #pragma unroll
        for (int d = 0; d < 16; ++d) t1[d] = 0.f;
        float rsum = 0.f;
        for (int j = 0; j < IPT; ++j) {
            int i = isub * IPT + j;
            float a_i = apL[i];
            const float4* w4 = (const float4*)(Wg + (size_t)(i * NC + c) * 16);
            float wa[16], ma[16];
            ((float4*)wa)[0] = w4[0]; ((float4*)wa)[1] = w4[1];
            ((float4*)wa)[2] = w4[2]; ((float4*)wa)[3] = w4[3];
            const float4* mp4 = (const float4*)(MpL + i * 16);
            ((float4*)ma)[0] = mp4[0]; ((float4*)ma)[1] = mp4[1];
            ((float4*)ma)[2] = mp4[2]; ((float4*)ma)[3] = mp4[3];
            float v[16];
            #pragma unroll
            for (int p = 0; p < 4; ++p)
                #pragma unroll
                for (int r = 0; r < 4; ++r) {
                    float acc = ma[p * 4 + 0] * wa[0 * 4 + r];
                    acc = fmaf(ma[p * 4 + 1], wa[1 * 4 + r], acc);
                    acc = fmaf(ma[p * 4 + 2], wa[2 * 4 + r], acc);
                    acc = fmaf(ma[p * 4 + 3], wa[3 * 4 + r], acc);
                    v[p * 4 + r] = acc;
                }
            float lp = Kc;
            #pragma unroll
            for (int d = 0; d < 16; ++d) {
                float df = v[d] - Mreg[d];
                lp = fmaf(-df * df, i2[d], lp);
            }
            // softmax over the 32 caps held by this half-wave
            float mx = lp;
            mx = fmaxf(mx, __shfl_xor(mx, 16)); mx = fmaxf(mx, __shfl_xor(mx, 8));
            mx = fmaxf(mx, __shfl_xor(mx, 4));  mx = fmaxf(mx, __shfl_xor(mx, 2));
            mx = fmaxf(mx, __shfl_xor(mx, 1));
            float ex = expf(lp - mx);
            float s = ex;
            s += __shfl_xor(s, 16); s += __shfl_xor(s, 8);
            s += __shfl_xor(s, 4);  s += __shfl_xor(s, 2);
            s += __shfl_xor(s, 1);
            float r = ex / s;
            float rw = r * a_i;
            rsum += rw;
            #pragma unroll
            for (int d = 0; d < 16; ++d) t1[d] = fmaf(rw, v[d], t1[d]);
        }
        rsum += __shfl_xor(rsum, 32);
        #pragma unroll
        for (int d = 0; d < 16; ++d) t1[d] += __shfl_xor(t1[d], 32);
        if ((t & 32) == 0) {
            atomicAdd(&RsumL[c], rsum);
            #pragma unroll
            for (int d = 0; d < 16; ++d) atomicAdd(&T1L[c * 16 + d], t1[d]);
        }
        __syncthreads();
        stats(1.0f + (float)it);   // inv_temp = 1 + it
        __syncthreads();
    }

    // ---- epilogue: out[b,ho,wo,c,0:16]=M, out[...,16]=sigmoid(a_j) ----
    for (int idx = t; idx < NC * 17; idx += NTHREADS) {
        int cc = idx / 17;
        int e = idx - cc * 17;
        float val = (e < 16) ? ML[cc * 17 + e] : aoutL[cc];
        out[(size_t)bid * (NC * 17) + idx] = val;
    }
}

extern "C" void kernel_launch(void* const* d_in, const int* in_sizes, int n_in,
                              void* d_out, int out_size, void* d_ws, size_t ws_size,
                              hipStream_t stream) {
    const float* x  = (const float*)d_in[0];
    const float* W  = (const float*)d_in[1];
    const float* bv = (const float*)d_in[2];
    const float* ba = (const float*)d_in[3];
    float* out = (float*)d_out;
    // grid = B*Ho*Wo = 2*12*12 = 288 positions, one block each
    caps_em_kernel<<<288, NTHREADS, 0, stream>>>(x, W, bv, ba, out);
}